// Round 7
// baseline (340.859 us; speedup 1.0000x reference)
//
#include <hip/hip_runtime.h>
#include <hip/hip_fp16.h>
#include <math.h>

#define D 128

typedef __attribute__((ext_vector_type(8))) _Float16 half8;
typedef __attribute__((ext_vector_type(4))) float f32x4;

// ---------------- graph build ----------------

// rank[e] = arrival order of edge e within its dst bucket; cnt[d] = in-degree
__global__ void count_rank_kernel(const int* __restrict__ dst, int* __restrict__ cnt,
                                  int* __restrict__ rank, int E) {
    int e0 = (blockIdx.x * blockDim.x + threadIdx.x) * 8;
    if (e0 + 7 < E) {
        int4 da = *(const int4*)(dst + e0);
        int4 db = *(const int4*)(dst + e0 + 4);
        int4 ra, rb;
        ra.x = atomicAdd(&cnt[da.x], 1);
        ra.y = atomicAdd(&cnt[da.y], 1);
        ra.z = atomicAdd(&cnt[da.z], 1);
        ra.w = atomicAdd(&cnt[da.w], 1);
        rb.x = atomicAdd(&cnt[db.x], 1);
        rb.y = atomicAdd(&cnt[db.y], 1);
        rb.z = atomicAdd(&cnt[db.z], 1);
        rb.w = atomicAdd(&cnt[db.w], 1);
        *(int4*)(rank + e0)     = ra;
        *(int4*)(rank + e0 + 4) = rb;
    } else {
        for (int e = e0; e < E; ++e) rank[e] = atomicAdd(&cnt[dst[e]], 1);
    }
}

// single-block scan, 4 elems/thread: cnt[N] -> rowptr[N+1]; dinv[i]=rsqrt(cnt[i]+1)
__global__ __launch_bounds__(1024) void scan_kernel(const int* __restrict__ cnt,
                                                    int* __restrict__ rowptr,
                                                    float* __restrict__ dinv,
                                                    int N) {
    __shared__ int wsum[16];
    __shared__ int carry_s;
    int tid  = threadIdx.x;
    int lane = tid & 63;
    int wid  = tid >> 6;
    if (tid == 0) carry_s = 0;
    __syncthreads();
    for (int base = 0; base < N; base += 4096) {
        int i = base + tid * 4;
        int4 v = make_int4(0, 0, 0, 0);
        if (i + 3 < N) v = *(const int4*)(cnt + i);
        else {
            if (i + 0 < N) v.x = cnt[i + 0];
            if (i + 1 < N) v.y = cnt[i + 1];
            if (i + 2 < N) v.z = cnt[i + 2];
            if (i + 3 < N) v.w = cnt[i + 3];
        }
        int s0 = v.x, s1 = s0 + v.y, s2 = s1 + v.z, s3 = s2 + v.w;
        int sc = s3;
        #pragma unroll
        for (int off = 1; off < 64; off <<= 1) {
            int t = __shfl_up(sc, off, 64);
            if (lane >= off) sc += t;
        }
        if (lane == 63) wsum[wid] = sc;
        __syncthreads();
        if (tid < 16) {
            int w = wsum[tid];
            #pragma unroll
            for (int off = 1; off < 16; off <<= 1) {
                int t = __shfl_up(w, off, 64);
                if (tid >= off) w += t;
            }
            wsum[tid] = w;
        }
        __syncthreads();
        int waveoff = (wid > 0) ? wsum[wid - 1] : 0;
        int excl = carry_s + waveoff + (sc - s3);
        if (i + 0 < N) { rowptr[i + 0] = excl;      dinv[i + 0] = rsqrtf((float)v.x + 1.0f); }
        if (i + 1 < N) { rowptr[i + 1] = excl + s0; dinv[i + 1] = rsqrtf((float)v.y + 1.0f); }
        if (i + 2 < N) { rowptr[i + 2] = excl + s1; dinv[i + 2] = rsqrtf((float)v.z + 1.0f); }
        if (i + 3 < N) { rowptr[i + 3] = excl + s2; dinv[i + 3] = rsqrtf((float)v.w + 1.0f); }
        __syncthreads();
        if (tid == 0) carry_s += wsum[15];
        __syncthreads();
    }
    if (tid == 0) rowptr[N] = carry_s;
}

// atomic-free scatter: col[rowptr[dst[e]] + rank[e]] = src[e]
__global__ void fill_kernel(const int* __restrict__ src, const int* __restrict__ dst,
                            const int* __restrict__ rank, const int* __restrict__ rowptr,
                            int* __restrict__ col, int E) {
    int e0 = (blockIdx.x * blockDim.x + threadIdx.x) * 8;
    if (e0 + 7 < E) {
        int4 da = *(const int4*)(dst + e0);
        int4 db = *(const int4*)(dst + e0 + 4);
        int4 ra = *(const int4*)(rank + e0);
        int4 rb = *(const int4*)(rank + e0 + 4);
        int4 sa = *(const int4*)(src + e0);
        int4 sb = *(const int4*)(src + e0 + 4);
        col[rowptr[da.x] + ra.x] = sa.x;
        col[rowptr[da.y] + ra.y] = sa.y;
        col[rowptr[da.z] + ra.z] = sa.z;
        col[rowptr[da.w] + ra.w] = sa.w;
        col[rowptr[db.x] + rb.x] = sb.x;
        col[rowptr[db.y] + rb.y] = sb.y;
        col[rowptr[db.z] + rb.z] = sb.z;
        col[rowptr[db.w] + rb.w] = sb.w;
    } else {
        for (int e = e0; e < E; ++e) col[rowptr[dst[e]] + rank[e]] = src[e];
    }
}

// ---------------- W transpose+convert: WhT[l][n][k] = (half)Wl[k][n] ----------------

__global__ void convw_kernel(const float* __restrict__ W1, const float* __restrict__ W2,
                             const float* __restrict__ W3, __half* __restrict__ WhT) {
    int i = blockIdx.x * blockDim.x + threadIdx.x;  // 3*16384
    int l = i >> 14;
    int j = i & 16383;
    int n = j >> 7, k = j & 127;
    const float* W = (l == 0) ? W1 : (l == 1) ? W2 : W3;
    WhT[(size_t)i] = __float2half(W[(size_t)k * D + n]);
}

// ---------------- MFMA GEMM: Y[i] = (half) dinv[i] * (X[i] @ W) ----------------

__global__ __launch_bounds__(256) void gemm_mfma_f32(const float* __restrict__ X,
                                                     const __half* __restrict__ WhT,
                                                     const float* __restrict__ dinv,
                                                     __half* __restrict__ Y, int M) {
    int tid  = threadIdx.x;
    int wave = tid >> 6;
    int lane = tid & 63;
    int quad = lane >> 4;
    int l16  = lane & 15;
    int m0   = blockIdx.x * 64 + wave * 16;
    if (m0 >= M) return;

    f32x4 acc[8];
    #pragma unroll
    for (int t = 0; t < 8; ++t) acc[t] = (f32x4)0.0f;

    const float* xrow = X + (size_t)(m0 + l16) * D;

    #pragma unroll
    for (int ks = 0; ks < 4; ++ks) {
        int k0 = ks * 32 + quad * 8;
        float4 x0 = *(const float4*)(xrow + k0);
        float4 x1 = *(const float4*)(xrow + k0 + 4);
        half8 a;
        a[0] = (_Float16)x0.x; a[1] = (_Float16)x0.y;
        a[2] = (_Float16)x0.z; a[3] = (_Float16)x0.w;
        a[4] = (_Float16)x1.x; a[5] = (_Float16)x1.y;
        a[6] = (_Float16)x1.z; a[7] = (_Float16)x1.w;
        #pragma unroll
        for (int t = 0; t < 8; ++t) {
            half8 b = *(const half8*)(WhT + (size_t)(t * 16 + l16) * D + k0);
            acc[t] = __builtin_amdgcn_mfma_f32_16x16x32_f16(a, b, acc[t], 0, 0, 0);
        }
    }

    float4 dv = *(const float4*)(dinv + m0 + quad * 4);
    float dvs[4] = {dv.x, dv.y, dv.z, dv.w};
    #pragma unroll
    for (int t = 0; t < 8; ++t) {
        #pragma unroll
        for (int r = 0; r < 4; ++r) {
            int grow = m0 + quad * 4 + r;
            Y[(size_t)grow * D + t * 16 + l16] = __float2half(acc[t][r] * dvs[r]);
        }
    }
}

__global__ __launch_bounds__(256) void gemm_mfma_f16(const __half* __restrict__ Xh,
                                                     const __half* __restrict__ WhT,
                                                     const float* __restrict__ dinv,
                                                     __half* __restrict__ Y, int M) {
    int tid  = threadIdx.x;
    int wave = tid >> 6;
    int lane = tid & 63;
    int quad = lane >> 4;
    int l16  = lane & 15;
    int m0   = blockIdx.x * 64 + wave * 16;
    if (m0 >= M) return;

    f32x4 acc[8];
    #pragma unroll
    for (int t = 0; t < 8; ++t) acc[t] = (f32x4)0.0f;

    const __half* xrow = Xh + (size_t)(m0 + l16) * D;

    #pragma unroll
    for (int ks = 0; ks < 4; ++ks) {
        int k0 = ks * 32 + quad * 8;
        half8 a = *(const half8*)(xrow + k0);
        #pragma unroll
        for (int t = 0; t < 8; ++t) {
            half8 b = *(const half8*)(WhT + (size_t)(t * 16 + l16) * D + k0);
            acc[t] = __builtin_amdgcn_mfma_f32_16x16x32_f16(a, b, acc[t], 0, 0, 0);
        }
    }

    float4 dv = *(const float4*)(dinv + m0 + quad * 4);
    float dvs[4] = {dv.x, dv.y, dv.z, dv.w};
    #pragma unroll
    for (int t = 0; t < 8; ++t) {
        #pragma unroll
        for (int r = 0; r < 4; ++r) {
            int grow = m0 + quad * 4 + r;
            Y[(size_t)grow * D + t * 16 + l16] = __float2half(acc[t][r] * dvs[r]);
        }
    }
}

// ---------------- aggregation ----------------
// Wave = 1 node; 4 lane-groups of 16; group g gathers row c[j+g] with 16 B/lane.
// UNIFORM control flow: out-of-range lanes hold dummy row N (zeroed), so the
// j-loop needs no predicates and no divergent shuffles. Cross-group combine =
// shfl_xor(16/32); self-loop row added uniformly after the reduce.

__device__ __forceinline__ void acc_h8(float2 a[4], half8 v) {
    a[0].x += (float)v[0]; a[0].y += (float)v[1];
    a[1].x += (float)v[2]; a[1].y += (float)v[3];
    a[2].x += (float)v[4]; a[2].y += (float)v[5];
    a[3].x += (float)v[6]; a[3].y += (float)v[7];
}

template <bool FINAL>
__global__ __launch_bounds__(256) void aggregate_kernel(const __half* __restrict__ ys,
                                                        const int* __restrict__ rowptr,
                                                        const int* __restrict__ col,
                                                        const float* __restrict__ dinv,
                                                        const float* __restrict__ b,
                                                        __half* __restrict__ outh,
                                                        float* __restrict__ outf,
                                                        int N) {
    int gwave = (blockIdx.x * blockDim.x + threadIdx.x) >> 6;
    int lane  = threadIdx.x & 63;
    int g     = lane >> 4;   // lane group 0..3
    int l16   = lane & 15;
    if (gwave >= N) return;
    int row = gwave;
    int s = rowptr[row], e = rowptr[row + 1];

    float2 a[4];
    a[0] = a[1] = a[2] = a[3] = make_float2(0.f, 0.f);

    for (int base = s; base < e; base += 64) {
        int idx = base + lane;
        int myc = (idx < e) ? col[idx] : N;  // N = dummy zero row
        int nb  = min(64, e - base);
        #pragma unroll 4
        for (int j = 0; j < nb; j += 4) {
            int c = __shfl(myc, j + g);      // j+g <= 63 always; ragged tail -> row N (zeros)
            half8 v = *(const half8*)(ys + (size_t)c * D + (l16 << 3));
            acc_h8(a, v);
        }
    }

    // combine the 4 lane-groups
    #pragma unroll
    for (int k = 0; k < 4; ++k) {
        a[k].x += __shfl_xor(a[k].x, 16, 64);
        a[k].y += __shfl_xor(a[k].y, 16, 64);
        a[k].x += __shfl_xor(a[k].x, 32, 64);
        a[k].y += __shfl_xor(a[k].y, 32, 64);
    }

    // self-loop term, uniform on all lanes (same address per l16 across groups)
    half8 us = *(const half8*)(ys + (size_t)row * D + (l16 << 3));
    acc_h8(a, us);

    float dv = dinv[row];
    float4 b0 = *(const float4*)(b + (l16 << 3));
    float4 b1 = *(const float4*)(b + (l16 << 3) + 4);
    float r0 = b0.x + dv * a[0].x, r1 = b0.y + dv * a[0].y;
    float r2 = b0.z + dv * a[1].x, r3 = b0.w + dv * a[1].y;
    float r4 = b1.x + dv * a[2].x, r5 = b1.y + dv * a[2].y;
    float r6 = b1.z + dv * a[3].x, r7 = b1.w + dv * a[3].y;

    if (FINAL) {
        if (g == 0)
            *(float4*)(outf + (size_t)row * D + (l16 << 3)) = make_float4(r0, r1, r2, r3);
        else if (g == 1)
            *(float4*)(outf + (size_t)row * D + (l16 << 3) + 4) = make_float4(r4, r5, r6, r7);
    } else {
        if (g == 0) {
            __half2 h0 = __floats2half2_rn(fmaxf(r0, 0.f), fmaxf(r1, 0.f));
            __half2 h1 = __floats2half2_rn(fmaxf(r2, 0.f), fmaxf(r3, 0.f));
            __half2 h2 = __floats2half2_rn(fmaxf(r4, 0.f), fmaxf(r5, 0.f));
            __half2 h3 = __floats2half2_rn(fmaxf(r6, 0.f), fmaxf(r7, 0.f));
            uint4 pk;
            pk.x = *(unsigned int*)&h0; pk.y = *(unsigned int*)&h1;
            pk.z = *(unsigned int*)&h2; pk.w = *(unsigned int*)&h3;
            *(uint4*)(outh + (size_t)row * D + (l16 << 3)) = pk;
        }
    }
}

// ---------------- launch ----------------

extern "C" void kernel_launch(void* const* d_in, const int* in_sizes, int n_in,
                              void* d_out, int out_size, void* d_ws, size_t ws_size,
                              hipStream_t stream) {
    const float* x   = (const float*)d_in[0];
    const int*   ei  = (const int*)d_in[1];
    const float* W1  = (const float*)d_in[2];
    const float* b1  = (const float*)d_in[3];
    const float* W2  = (const float*)d_in[4];
    const float* b2  = (const float*)d_in[5];
    const float* W3  = (const float*)d_in[6];
    const float* b3  = (const float*)d_in[7];
    float* out = (float*)d_out;

    const int N = in_sizes[0] / D;
    const int E = in_sizes[1] / 2;
    const int* src = ei;
    const int* dst = ei + E;

    char* ws = (char*)d_ws;
    size_t off = 0;
    auto alloc = [&](size_t bytes) {
        void* p = ws + off;
        off = (off + bytes + 255) & ~(size_t)255;
        return p;
    };
    __half* ys    = (__half*)alloc((size_t)(N + 1) * D * sizeof(__half));  // +1 dummy zero row
    __half* hs    = (__half*)alloc((size_t)N * D * sizeof(__half));
    int*   cnt    = (int*)alloc((size_t)N * sizeof(int));
    int*   rowptr = (int*)alloc((size_t)(N + 1) * sizeof(int));
    float* dinv   = (float*)alloc((size_t)N * sizeof(float));
    int*   rank   = (int*)alloc((size_t)E * sizeof(int));
    int*   col    = (int*)alloc((size_t)E * sizeof(int));
    __half* WhT   = (__half*)alloc((size_t)3 * D * D * sizeof(__half));
    (void)ws_size; (void)n_in; (void)out_size;

    convw_kernel<<<(3 * D * D + 255) / 256, 256, 0, stream>>>(W1, W2, W3, WhT);

    hipMemsetAsync(cnt, 0, (size_t)N * sizeof(int), stream);
    hipMemsetAsync(ys + (size_t)N * D, 0, (size_t)D * sizeof(__half), stream);  // dummy row = 0
    const int egrid = ((E + 7) / 8 + 255) / 256;
    count_rank_kernel<<<egrid, 256, 0, stream>>>(dst, cnt, rank, E);
    scan_kernel<<<1, 1024, 0, stream>>>(cnt, rowptr, dinv, N);
    fill_kernel<<<egrid, 256, 0, stream>>>(src, dst, rank, rowptr, col, E);

    const int gemm_grid = (N + 63) / 64;
    const int agg_grid  = (N * 64 + 255) / 256;

    gemm_mfma_f32<<<gemm_grid, 256, 0, stream>>>(x, WhT, dinv, ys, N);
    aggregate_kernel<false><<<agg_grid, 256, 0, stream>>>(ys, rowptr, col, dinv, b1, hs, nullptr, N);
    gemm_mfma_f16<<<gemm_grid, 256, 0, stream>>>(hs, WhT + 16384, dinv, ys, N);
    aggregate_kernel<false><<<agg_grid, 256, 0, stream>>>(ys, rowptr, col, dinv, b2, hs, nullptr, N);
    gemm_mfma_f16<<<gemm_grid, 256, 0, stream>>>(hs, WhT + 32768, dinv, ys, N);
    aggregate_kernel<true><<<agg_grid, 256, 0, stream>>>(ys, rowptr, col, dinv, b3, nullptr, out, N);
}

// Round 8
// 337.988 us; speedup vs baseline: 1.0085x; 1.0085x over previous
//
#include <hip/hip_runtime.h>
#include <hip/hip_fp16.h>
#include <math.h>

#define D 128

typedef __attribute__((ext_vector_type(8))) _Float16 half8;
typedef __attribute__((ext_vector_type(4))) float f32x4;

// ---------------- graph build ----------------

// rank[e] = arrival order of edge e within its dst bucket; cnt[d] = in-degree
__global__ void count_rank_kernel(const int* __restrict__ dst, int* __restrict__ cnt,
                                  int* __restrict__ rank, int E) {
    int e0 = (blockIdx.x * blockDim.x + threadIdx.x) * 8;
    if (e0 + 7 < E) {
        int4 da = *(const int4*)(dst + e0);
        int4 db = *(const int4*)(dst + e0 + 4);
        int4 ra, rb;
        ra.x = atomicAdd(&cnt[da.x], 1);
        ra.y = atomicAdd(&cnt[da.y], 1);
        ra.z = atomicAdd(&cnt[da.z], 1);
        ra.w = atomicAdd(&cnt[da.w], 1);
        rb.x = atomicAdd(&cnt[db.x], 1);
        rb.y = atomicAdd(&cnt[db.y], 1);
        rb.z = atomicAdd(&cnt[db.z], 1);
        rb.w = atomicAdd(&cnt[db.w], 1);
        *(int4*)(rank + e0)     = ra;
        *(int4*)(rank + e0 + 4) = rb;
    } else {
        for (int e = e0; e < E; ++e) rank[e] = atomicAdd(&cnt[dst[e]], 1);
    }
}

// single-block scan, 4 elems/thread: cnt[N] -> rowptr[N+1]; dinv[i]=rsqrt(cnt[i]+1)
__global__ __launch_bounds__(1024) void scan_kernel(const int* __restrict__ cnt,
                                                    int* __restrict__ rowptr,
                                                    float* __restrict__ dinv,
                                                    int N) {
    __shared__ int wsum[16];
    __shared__ int carry_s;
    int tid  = threadIdx.x;
    int lane = tid & 63;
    int wid  = tid >> 6;
    if (tid == 0) carry_s = 0;
    __syncthreads();
    for (int base = 0; base < N; base += 4096) {
        int i = base + tid * 4;
        int4 v = make_int4(0, 0, 0, 0);
        if (i + 3 < N) v = *(const int4*)(cnt + i);
        else {
            if (i + 0 < N) v.x = cnt[i + 0];
            if (i + 1 < N) v.y = cnt[i + 1];
            if (i + 2 < N) v.z = cnt[i + 2];
            if (i + 3 < N) v.w = cnt[i + 3];
        }
        int s0 = v.x, s1 = s0 + v.y, s2 = s1 + v.z, s3 = s2 + v.w;
        int sc = s3;
        #pragma unroll
        for (int off = 1; off < 64; off <<= 1) {
            int t = __shfl_up(sc, off, 64);
            if (lane >= off) sc += t;
        }
        if (lane == 63) wsum[wid] = sc;
        __syncthreads();
        if (tid < 16) {
            int w = wsum[tid];
            #pragma unroll
            for (int off = 1; off < 16; off <<= 1) {
                int t = __shfl_up(w, off, 64);
                if (tid >= off) w += t;
            }
            wsum[tid] = w;
        }
        __syncthreads();
        int waveoff = (wid > 0) ? wsum[wid - 1] : 0;
        int excl = carry_s + waveoff + (sc - s3);
        if (i + 0 < N) { rowptr[i + 0] = excl;      dinv[i + 0] = rsqrtf((float)v.x + 1.0f); }
        if (i + 1 < N) { rowptr[i + 1] = excl + s0; dinv[i + 1] = rsqrtf((float)v.y + 1.0f); }
        if (i + 2 < N) { rowptr[i + 2] = excl + s1; dinv[i + 2] = rsqrtf((float)v.z + 1.0f); }
        if (i + 3 < N) { rowptr[i + 3] = excl + s2; dinv[i + 3] = rsqrtf((float)v.w + 1.0f); }
        __syncthreads();
        if (tid == 0) carry_s += wsum[15];
        __syncthreads();
    }
    if (tid == 0) rowptr[N] = carry_s;
}

// atomic-free scatter: col[rowptr[dst[e]] + rank[e]] = src[e]
__global__ void fill_kernel(const int* __restrict__ src, const int* __restrict__ dst,
                            const int* __restrict__ rank, const int* __restrict__ rowptr,
                            int* __restrict__ col, int E) {
    int e0 = (blockIdx.x * blockDim.x + threadIdx.x) * 8;
    if (e0 + 7 < E) {
        int4 da = *(const int4*)(dst + e0);
        int4 db = *(const int4*)(dst + e0 + 4);
        int4 ra = *(const int4*)(rank + e0);
        int4 rb = *(const int4*)(rank + e0 + 4);
        int4 sa = *(const int4*)(src + e0);
        int4 sb = *(const int4*)(src + e0 + 4);
        col[rowptr[da.x] + ra.x] = sa.x;
        col[rowptr[da.y] + ra.y] = sa.y;
        col[rowptr[da.z] + ra.z] = sa.z;
        col[rowptr[da.w] + ra.w] = sa.w;
        col[rowptr[db.x] + rb.x] = sb.x;
        col[rowptr[db.y] + rb.y] = sb.y;
        col[rowptr[db.z] + rb.z] = sb.z;
        col[rowptr[db.w] + rb.w] = sb.w;
    } else {
        for (int e = e0; e < E; ++e) col[rowptr[dst[e]] + rank[e]] = src[e];
    }
}

// ---------------- W transpose+convert: WhT[l][n][k] = (half)Wl[k][n] ----------------

__global__ void convw_kernel(const float* __restrict__ W1, const float* __restrict__ W2,
                             const float* __restrict__ W3, __half* __restrict__ WhT) {
    int i = blockIdx.x * blockDim.x + threadIdx.x;  // 3*16384
    int l = i >> 14;
    int j = i & 16383;
    int n = j >> 7, k = j & 127;
    const float* W = (l == 0) ? W1 : (l == 1) ? W2 : W3;
    WhT[(size_t)i] = __float2half(W[(size_t)k * D + n]);
}

// ---------------- layer-1 GEMM: ys = (half) dinv * (x @ W1), x fp32 ----------------
// Zero-LDS; wave owns 16 rows. A[m=l16][k=quad*8+j]; B[k][n=l16]; C/D row=quad*4+r, col=l16.

__global__ __launch_bounds__(256) void gemm_mfma_f32(const float* __restrict__ X,
                                                     const __half* __restrict__ WhT,
                                                     const float* __restrict__ dinv,
                                                     __half* __restrict__ Y, int M) {
    int tid  = threadIdx.x;
    int wave = tid >> 6;
    int lane = tid & 63;
    int quad = lane >> 4;
    int l16  = lane & 15;
    int m0   = blockIdx.x * 64 + wave * 16;
    if (m0 >= M) return;

    f32x4 acc[8];
    #pragma unroll
    for (int t = 0; t < 8; ++t) acc[t] = (f32x4)0.0f;

    const float* xrow = X + (size_t)(m0 + l16) * D;

    #pragma unroll
    for (int ks = 0; ks < 4; ++ks) {
        int k0 = ks * 32 + quad * 8;
        float4 x0 = *(const float4*)(xrow + k0);
        float4 x1 = *(const float4*)(xrow + k0 + 4);
        half8 a;
        a[0] = (_Float16)x0.x; a[1] = (_Float16)x0.y;
        a[2] = (_Float16)x0.z; a[3] = (_Float16)x0.w;
        a[4] = (_Float16)x1.x; a[5] = (_Float16)x1.y;
        a[6] = (_Float16)x1.z; a[7] = (_Float16)x1.w;
        #pragma unroll
        for (int t = 0; t < 8; ++t) {
            half8 b = *(const half8*)(WhT + (size_t)(t * 16 + l16) * D + k0);
            acc[t] = __builtin_amdgcn_mfma_f32_16x16x32_f16(a, b, acc[t], 0, 0, 0);
        }
    }

    float4 dv = *(const float4*)(dinv + m0 + quad * 4);
    float dvs[4] = {dv.x, dv.y, dv.z, dv.w};
    #pragma unroll
    for (int t = 0; t < 8; ++t) {
        #pragma unroll
        for (int r = 0; r < 4; ++r) {
            int grow = m0 + quad * 4 + r;
            Y[(size_t)grow * D + t * 16 + l16] = __float2half(acc[t][r] * dvs[r]);
        }
    }
}

// ---------------- fused aggregate_l + gemm_{l+1} ----------------
// ysout = dinv * ( relu(b_l + dinv*(ysin self+gather)) @ W_{l+1} )
// Wave owns 16 output rows. Lane (l16,quad) aggregates cols {ks*32+quad*8..+8}
// of node m0+l16 in fp32 (4x half8 chunk gathers per neighbor, exact per-lane
// trip count), then converts to the MFMA A-fragment in-register. No hs buffer.

__global__ __launch_bounds__(256) void fused_agg_gemm(const __half* __restrict__ ysin,
                                                      const int* __restrict__ rowptr,
                                                      const int* __restrict__ col,
                                                      const float* __restrict__ dinv,
                                                      const float* __restrict__ bias,
                                                      const __half* __restrict__ WhT,
                                                      __half* __restrict__ ysout, int M) {
    int tid  = threadIdx.x;
    int wave = tid >> 6;
    int lane = tid & 63;
    int quad = lane >> 4;
    int l16  = lane & 15;
    int m0   = blockIdx.x * 64 + wave * 16;
    if (m0 >= M) return;

    int n = m0 + l16;
    int s = rowptr[n], e = rowptr[n + 1];

    float acc[4][8];
    #pragma unroll
    for (int ks = 0; ks < 4; ++ks)
        #pragma unroll
        for (int j = 0; j < 8; ++j) acc[ks][j] = 0.0f;

    const __half* basep = ysin + quad * 8;  // lane's chunk offset within a row
    for (int i = s; i < e; ++i) {
        int c = col[i];
        const __half* r = basep + (size_t)c * D;
        half8 v0 = *(const half8*)(r);
        half8 v1 = *(const half8*)(r + 32);
        half8 v2 = *(const half8*)(r + 64);
        half8 v3 = *(const half8*)(r + 96);
        #pragma unroll
        for (int j = 0; j < 8; ++j) {
            acc[0][j] += (float)v0[j];
            acc[1][j] += (float)v1[j];
            acc[2][j] += (float)v2[j];
            acc[3][j] += (float)v3[j];
        }
    }
    {   // self-loop row
        const __half* r = basep + (size_t)n * D;
        half8 v0 = *(const half8*)(r);
        half8 v1 = *(const half8*)(r + 32);
        half8 v2 = *(const half8*)(r + 64);
        half8 v3 = *(const half8*)(r + 96);
        #pragma unroll
        for (int j = 0; j < 8; ++j) {
            acc[0][j] += (float)v0[j];
            acc[1][j] += (float)v1[j];
            acc[2][j] += (float)v2[j];
            acc[3][j] += (float)v3[j];
        }
    }

    // bias + dinv + relu -> A fragments (fp16)
    float dv = dinv[n];
    half8 a[4];
    #pragma unroll
    for (int ks = 0; ks < 4; ++ks) {
        const float* bp = bias + ks * 32 + quad * 8;
        float4 bq0 = *(const float4*)(bp);
        float4 bq1 = *(const float4*)(bp + 4);
        float t0 = fmaxf(bq0.x + dv * acc[ks][0], 0.f);
        float t1 = fmaxf(bq0.y + dv * acc[ks][1], 0.f);
        float t2 = fmaxf(bq0.z + dv * acc[ks][2], 0.f);
        float t3 = fmaxf(bq0.w + dv * acc[ks][3], 0.f);
        float t4 = fmaxf(bq1.x + dv * acc[ks][4], 0.f);
        float t5 = fmaxf(bq1.y + dv * acc[ks][5], 0.f);
        float t6 = fmaxf(bq1.z + dv * acc[ks][6], 0.f);
        float t7 = fmaxf(bq1.w + dv * acc[ks][7], 0.f);
        a[ks][0] = (_Float16)t0; a[ks][1] = (_Float16)t1;
        a[ks][2] = (_Float16)t2; a[ks][3] = (_Float16)t3;
        a[ks][4] = (_Float16)t4; a[ks][5] = (_Float16)t5;
        a[ks][6] = (_Float16)t6; a[ks][7] = (_Float16)t7;
    }

    f32x4 o[8];
    #pragma unroll
    for (int t = 0; t < 8; ++t) o[t] = (f32x4)0.0f;
    #pragma unroll
    for (int ks = 0; ks < 4; ++ks) {
        int k0 = ks * 32 + quad * 8;
        #pragma unroll
        for (int t = 0; t < 8; ++t) {
            half8 b = *(const half8*)(WhT + (size_t)(t * 16 + l16) * D + k0);
            o[t] = __builtin_amdgcn_mfma_f32_16x16x32_f16(a[ks], b, o[t], 0, 0, 0);
        }
    }

    float4 dvo = *(const float4*)(dinv + m0 + quad * 4);
    float dvs[4] = {dvo.x, dvo.y, dvo.z, dvo.w};
    #pragma unroll
    for (int t = 0; t < 8; ++t) {
        #pragma unroll
        for (int r = 0; r < 4; ++r) {
            int grow = m0 + quad * 4 + r;
            ysout[(size_t)grow * D + t * 16 + l16] = __float2half(o[t][r] * dvs[r]);
        }
    }
}

// ---------------- final aggregation: out = b + dinv*(ys self+gather), fp32 ----------------
// Wave = 1 node; 4 lane-groups of 16 gather 4 rows per load (16 B/lane); exact
// predicated tail (uniform branch, clamped shuffle index, zero-weighted dup loads).

__device__ __forceinline__ void acc_h8(float2 a[4], half8 v) {
    a[0].x += (float)v[0]; a[0].y += (float)v[1];
    a[1].x += (float)v[2]; a[1].y += (float)v[3];
    a[2].x += (float)v[4]; a[2].y += (float)v[5];
    a[3].x += (float)v[6]; a[3].y += (float)v[7];
}

__global__ __launch_bounds__(256) void aggregate_final(const __half* __restrict__ ys,
                                                       const int* __restrict__ rowptr,
                                                       const int* __restrict__ col,
                                                       const float* __restrict__ dinv,
                                                       const float* __restrict__ b,
                                                       float* __restrict__ outf,
                                                       int N) {
    int gwave = (blockIdx.x * blockDim.x + threadIdx.x) >> 6;
    int lane  = threadIdx.x & 63;
    int g     = lane >> 4;
    int l16   = lane & 15;
    if (gwave >= N) return;
    int row = gwave;
    int s = rowptr[row], e = rowptr[row + 1];

    float2 a[4];
    a[0] = a[1] = a[2] = a[3] = make_float2(0.f, 0.f);

    for (int base = s; base < e; base += 64) {
        int idx = base + lane;
        int myc = (idx < e) ? col[idx] : 0;
        int nb  = min(64, e - base);
        int nb4 = nb & ~3;
        #pragma unroll 4
        for (int j = 0; j < nb4; j += 4) {
            int c = __shfl(myc, j + g);
            half8 v = *(const half8*)(ys + (size_t)c * D + (l16 << 3));
            acc_h8(a, v);
        }
        int rem = nb - nb4;
        if (rem) {  // wave-uniform branch
            int jj = nb4 + min(g, rem - 1);  // <= nb-1, always valid
            int c = __shfl(myc, jj);
            half8 v = *(const half8*)(ys + (size_t)c * D + (l16 << 3));
            float m = (g < rem) ? 1.f : 0.f;
            a[0].x += m * (float)v[0]; a[0].y += m * (float)v[1];
            a[1].x += m * (float)v[2]; a[1].y += m * (float)v[3];
            a[2].x += m * (float)v[4]; a[2].y += m * (float)v[5];
            a[3].x += m * (float)v[6]; a[3].y += m * (float)v[7];
        }
    }

    #pragma unroll
    for (int k = 0; k < 4; ++k) {
        a[k].x += __shfl_xor(a[k].x, 16, 64);
        a[k].y += __shfl_xor(a[k].y, 16, 64);
        a[k].x += __shfl_xor(a[k].x, 32, 64);
        a[k].y += __shfl_xor(a[k].y, 32, 64);
    }

    half8 us = *(const half8*)(ys + (size_t)row * D + (l16 << 3));
    acc_h8(a, us);

    float dv = dinv[row];
    float4 b0 = *(const float4*)(b + (l16 << 3));
    float4 b1 = *(const float4*)(b + (l16 << 3) + 4);
    float r0 = b0.x + dv * a[0].x, r1 = b0.y + dv * a[0].y;
    float r2 = b0.z + dv * a[1].x, r3 = b0.w + dv * a[1].y;
    float r4 = b1.x + dv * a[2].x, r5 = b1.y + dv * a[2].y;
    float r6 = b1.z + dv * a[3].x, r7 = b1.w + dv * a[3].y;

    if (g == 0)
        *(float4*)(outf + (size_t)row * D + (l16 << 3)) = make_float4(r0, r1, r2, r3);
    else if (g == 1)
        *(float4*)(outf + (size_t)row * D + (l16 << 3) + 4) = make_float4(r4, r5, r6, r7);
}

// ---------------- launch ----------------

extern "C" void kernel_launch(void* const* d_in, const int* in_sizes, int n_in,
                              void* d_out, int out_size, void* d_ws, size_t ws_size,
                              hipStream_t stream) {
    const float* x   = (const float*)d_in[0];
    const int*   ei  = (const int*)d_in[1];
    const float* W1  = (const float*)d_in[2];
    const float* b1  = (const float*)d_in[3];
    const float* W2  = (const float*)d_in[4];
    const float* b2  = (const float*)d_in[5];
    const float* W3  = (const float*)d_in[6];
    const float* b3  = (const float*)d_in[7];
    float* out = (float*)d_out;

    const int N = in_sizes[0] / D;
    const int E = in_sizes[1] / 2;
    const int* src = ei;
    const int* dst = ei + E;

    char* ws = (char*)d_ws;
    size_t off = 0;
    auto alloc = [&](size_t bytes) {
        void* p = ws + off;
        off = (off + bytes + 255) & ~(size_t)255;
        return p;
    };
    __half* ysA   = (__half*)alloc((size_t)N * D * sizeof(__half));
    __half* ysB   = (__half*)alloc((size_t)N * D * sizeof(__half));
    int*   cnt    = (int*)alloc((size_t)N * sizeof(int));
    int*   rowptr = (int*)alloc((size_t)(N + 1) * sizeof(int));
    float* dinv   = (float*)alloc((size_t)N * sizeof(float));
    int*   rank   = (int*)alloc((size_t)E * sizeof(int));
    int*   col    = (int*)alloc((size_t)E * sizeof(int));
    __half* WhT   = (__half*)alloc((size_t)3 * D * D * sizeof(__half));
    (void)ws_size; (void)n_in; (void)out_size;

    convw_kernel<<<(3 * D * D + 255) / 256, 256, 0, stream>>>(W1, W2, W3, WhT);

    hipMemsetAsync(cnt, 0, (size_t)N * sizeof(int), stream);
    const int egrid = ((E + 7) / 8 + 255) / 256;
    count_rank_kernel<<<egrid, 256, 0, stream>>>(dst, cnt, rank, E);
    scan_kernel<<<1, 1024, 0, stream>>>(cnt, rowptr, dinv, N);
    fill_kernel<<<egrid, 256, 0, stream>>>(src, dst, rank, rowptr, col, E);

    const int tile_grid = (N + 63) / 64;
    const int agg_grid  = (N * 64 + 255) / 256;

    gemm_mfma_f32<<<tile_grid, 256, 0, stream>>>(x, WhT, dinv, ysA, N);
    fused_agg_gemm<<<tile_grid, 256, 0, stream>>>(ysA, rowptr, col, dinv, b1, WhT + 16384, ysB, N);
    fused_agg_gemm<<<tile_grid, 256, 0, stream>>>(ysB, rowptr, col, dinv, b2, WhT + 32768, ysA, N);
    aggregate_final<<<agg_grid, 256, 0, stream>>>(ysA, rowptr, col, dinv, b3, out, N);
}